// Round 1
// baseline (128.343 us; speedup 1.0000x reference)
//
#include <hip/hip_runtime.h>
#include <math.h>

#define B_  8
#define S_  2048
#define H_  256
#define HK_ 128
#define P_  64
#define NQ_ 20
#define M_  (B_*S_)          // 16384 rows
#define ACC_STRIDE (41*64)   // per-batch: G[20][64], E[20][64], T[64]

// ---------------------------------------------------------------------------
// Kernel A: dual MLP (sim / conf selected by blockIdx.y).
// GEMM [16384,256] x [256,128] tiled: 64 rows/block, all 128 cols, 4x8/thread.
// Fused epilogue: relu(h+b1)·w2 partial dot + shfl reduce -> sim / sigmoid->conf.
// ---------------------------------------------------------------------------
__launch_bounds__(256)
__global__ void mlp_kernel(const float* __restrict__ fx,
                           const float* __restrict__ sw1, const float* __restrict__ sb1,
                           const float* __restrict__ sw2, const float* __restrict__ sb2,
                           const float* __restrict__ cw1, const float* __restrict__ cb1,
                           const float* __restrict__ cw2, const float* __restrict__ cb2,
                           float* __restrict__ sim, float* __restrict__ conf)
{
    const int tid = threadIdx.x;
    const int tx = tid & 15;     // col group: cols tx*8 .. tx*8+7
    const int ty = tid >> 4;     // row group: rows ty*4 .. ty*4+3
    const int row0 = blockIdx.x * 64;
    const bool isSim = (blockIdx.y == 0);
    const float* w1 = isSim ? sw1 : cw1;
    const float* b1 = isSim ? sb1 : cb1;
    const float* w2 = isSim ? sw2 : cw2;
    const float  b2v = isSim ? sb2[0] : cb2[0];

    __shared__ float As[16][68];   // transposed A tile, padded (16B-aligned rows)
    __shared__ float Bs[16][128];

    float acc[4][8];
    #pragma unroll
    for (int r = 0; r < 4; ++r)
        #pragma unroll
        for (int c = 0; c < 8; ++c) acc[r][c] = 0.f;

    const int arow = tid >> 2;        // 0..63
    const int akc  = tid & 3;         // 0..3 (k-chunk of 4)
    const int bk   = tid >> 5;        // 0..7
    const int bc4  = (tid & 31) * 4;  // col offset

    for (int kb = 0; kb < H_; kb += 16) {
        float4 av  = *(const float4*)(fx + (size_t)(row0 + arow) * H_ + kb + akc * 4);
        float4 bv0 = *(const float4*)(w1 + (size_t)(kb + bk) * HK_ + bc4);
        float4 bv1 = *(const float4*)(w1 + (size_t)(kb + 8 + bk) * HK_ + bc4);
        __syncthreads();               // previous iter's reads done
        As[akc*4+0][arow] = av.x;
        As[akc*4+1][arow] = av.y;
        As[akc*4+2][arow] = av.z;
        As[akc*4+3][arow] = av.w;
        *(float4*)&Bs[bk  ][bc4] = bv0;
        *(float4*)&Bs[bk+8][bc4] = bv1;
        __syncthreads();
        #pragma unroll
        for (int k = 0; k < 16; ++k) {
            float4 a4  = *(const float4*)&As[k][ty*4];
            float4 b40 = *(const float4*)&Bs[k][tx*8];
            float4 b41 = *(const float4*)&Bs[k][tx*8+4];
            float a[4]  = {a4.x, a4.y, a4.z, a4.w};
            float bb[8] = {b40.x,b40.y,b40.z,b40.w,b41.x,b41.y,b41.z,b41.w};
            #pragma unroll
            for (int r = 0; r < 4; ++r)
                #pragma unroll
                for (int c = 0; c < 8; ++c)
                    acc[r][c] = fmaf(a[r], bb[c], acc[r][c]);
        }
    }

    // layer-2 epilogue: partial[r] = sum_c relu(h+b1)*w2 over this thread's 8 cols
    float partial[4] = {0.f, 0.f, 0.f, 0.f};
    #pragma unroll
    for (int c = 0; c < 8; ++c) {
        int col = tx*8 + c;
        float b1c = b1[col];
        float w2c = w2[col];
        #pragma unroll
        for (int r = 0; r < 4; ++r)
            partial[r] += fmaxf(acc[r][c] + b1c, 0.f) * w2c;
    }
    // reduce across the 16 col-group threads (consecutive lanes, width-16 segments)
    #pragma unroll
    for (int off = 8; off >= 1; off >>= 1)
        #pragma unroll
        for (int r = 0; r < 4; ++r)
            partial[r] += __shfl_down(partial[r], off, 16);

    if (tx == 0) {
        #pragma unroll
        for (int r = 0; r < 4; ++r) {
            int grow = row0 + ty*4 + r;
            float v = partial[r] + b2v;
            if (isSim) sim[grow] = v;
            else       conf[grow] = 1.0f / (1.0f + expf(-v));
        }
    }
}

// ---------------------------------------------------------------------------
// Kernel B1: per-(b,q) softmax denominator: (S - n_q) + sum_{q_i=q} e^{sim_i}
// ---------------------------------------------------------------------------
__global__ void denom_kernel(const float* __restrict__ sim, const int* __restrict__ questions,
                             float* __restrict__ denom)
{
    const int b = blockIdx.x / NQ_, q = blockIdx.x % NQ_;
    const float* simb = sim + b * S_;
    const int*   qb   = questions + b * S_;
    const int tid = threadIdx.x;
    float w = 0.f; int cnt = 0;
    for (int i = tid; i < S_; i += 256) {
        if (qb[i] == q) { w += expf(simb[i]); cnt++; }
    }
    #pragma unroll
    for (int off = 32; off >= 1; off >>= 1) {
        w   += __shfl_down(w, off, 64);
        cnt += __shfl_down(cnt, off, 64);
    }
    __shared__ float ws4[4];
    __shared__ int   cs4[4];
    if ((tid & 63) == 0) { ws4[tid >> 6] = w; cs4[tid >> 6] = cnt; }
    __syncthreads();
    if (tid == 0) {
        float W = ws4[0] + ws4[1] + ws4[2] + ws4[3];
        int   n = cs4[0] + cs4[1] + cs4[2] + cs4[3];
        denom[blockIdx.x] = (float)(S_ - n) + W;
    }
}

// ---------------------------------------------------------------------------
// Kernel B2: bucketed sums over param_x. Per block: batch b, 64-row chunk.
// Per-group (64 lanes) LDS accumulators G_q, E_q + register T; atomicAdd to ws.
// ---------------------------------------------------------------------------
__launch_bounds__(256)
__global__ void accum_kernel(const float* __restrict__ sim, const int* __restrict__ questions,
                             const float* __restrict__ px, float* __restrict__ ws_acc)
{
    const int b = blockIdx.x;
    const int chunk = blockIdx.y;         // 32 chunks of 64 rows
    const int tid = threadIdx.x;
    const int lane = tid & 63;            // p index
    const int g = tid >> 6;               // group 0..3
    __shared__ float accs[4][ACC_STRIDE];
    for (int s = tid; s < 4 * ACC_STRIDE; s += 256) ((float*)accs)[s] = 0.f;
    __syncthreads();

    const float* simb = sim + b * S_;
    const int*   qb   = questions + b * S_;
    const float* pxb  = px + (size_t)b * S_ * P_;

    float Treg = 0.f;
    const int i0 = chunk * 64 + g;
    for (int t = 0; t < 16; ++t) {
        int i = i0 + 4 * t;
        int qi = qb[i];                       // uniform across group -> broadcast
        float e = expf(simb[i]);
        float v = pxb[(size_t)i * P_ + lane]; // coalesced 256B per group
        Treg += v;
        accs[g][qi * 64 + lane]        += v;       // G_q
        accs[g][(20 + qi) * 64 + lane] += e * v;   // E_q
    }
    accs[g][40 * 64 + lane] += Treg;               // T
    __syncthreads();

    float* dst = ws_acc + (size_t)b * ACC_STRIDE;
    for (int s = tid; s < ACC_STRIDE; s += 256) {
        float sum = accs[0][s] + accs[1][s] + accs[2][s] + accs[3][s];
        atomicAdd(dst + s, sum);
    }
}

// ---------------------------------------------------------------------------
// Kernel C: out = c*px + (1-c) * ((T - G_q + E_q) / denom_q), float4 per thread
// ---------------------------------------------------------------------------
__global__ void output_kernel(const float* __restrict__ px, const float* __restrict__ conf,
                              const int* __restrict__ questions, const float* __restrict__ ws_acc,
                              const float* __restrict__ denom, float* __restrict__ out)
{
    const int idx = blockIdx.x * 256 + threadIdx.x;  // float4 units, 262144 total
    const int row = idx >> 4;                        // b*S + s
    const int p4  = idx & 15;
    const int b   = row >> 11;                       // S = 2048
    const float c = conf[row];
    const int   q = questions[row];
    const float* accb = ws_acc + (size_t)b * ACC_STRIDE;
    const float4 T = *(const float4*)(accb + 40 * 64 + p4 * 4);
    const float4 G = *(const float4*)(accb + q * 64 + p4 * 4);
    const float4 E = *(const float4*)(accb + (20 + q) * 64 + p4 * 4);
    const float inv = 1.0f / denom[b * NQ_ + q];
    const float4 pv = ((const float4*)px)[idx];
    const float om = 1.0f - c;
    float4 o;
    o.x = c * pv.x + om * ((T.x - G.x + E.x) * inv);
    o.y = c * pv.y + om * ((T.y - G.y + E.y) * inv);
    o.z = c * pv.z + om * ((T.z - G.z + E.z) * inv);
    o.w = c * pv.w + om * ((T.w - G.w + E.w) * inv);
    ((float4*)out)[idx] = o;
}

// ---------------------------------------------------------------------------
extern "C" void kernel_launch(void* const* d_in, const int* in_sizes, int n_in,
                              void* d_out, int out_size, void* d_ws, size_t ws_size,
                              hipStream_t stream) {
    const float* fx  = (const float*)d_in[0];
    const float* px  = (const float*)d_in[1];
    const float* sw1 = (const float*)d_in[2];
    const float* sb1 = (const float*)d_in[3];
    const float* sw2 = (const float*)d_in[4];
    const float* sb2 = (const float*)d_in[5];
    const float* cw1 = (const float*)d_in[6];
    const float* cb1 = (const float*)d_in[7];
    const float* cw2 = (const float*)d_in[8];
    const float* cb2 = (const float*)d_in[9];
    const int* questions = (const int*)d_in[10];
    float* out = (float*)d_out;

    float* ws     = (float*)d_ws;
    float* sim    = ws;                  // 16384
    float* conf   = ws + 16384;          // 16384
    float* denom  = ws + 32768;          // 160
    float* ws_acc = ws + 33024;          // 8 * 2624 = 20992 (16B-aligned offset)

    hipMemsetAsync(ws_acc, 0, (size_t)B_ * ACC_STRIDE * sizeof(float), stream);

    mlp_kernel<<<dim3(M_ / 64, 2), 256, 0, stream>>>(fx, sw1, sb1, sw2, sb2,
                                                     cw1, cb1, cw2, cb2, sim, conf);
    denom_kernel<<<B_ * NQ_, 256, 0, stream>>>(sim, questions, denom);
    accum_kernel<<<dim3(B_, 32), 256, 0, stream>>>(sim, questions, px, ws_acc);
    output_kernel<<<(M_ * P_ / 4) / 256, 256, 0, stream>>>(px, conf, questions,
                                                           ws_acc, denom, out);
}

// Round 2
// 117.654 us; speedup vs baseline: 1.0909x; 1.0909x over previous
//
#include <hip/hip_runtime.h>
#include <math.h>

#define B_  8
#define S_  2048
#define H_  256
#define HK_ 128
#define P_  64
#define NQ_ 20
#define M_  (B_*S_)          // 16384 rows
// per-batch accumulator: G[20][64]@0, E[20][64]@1280, T[64]@2560, W[20]@2624, n[20]@2644, pad->2688
#define ACC_STRIDE 2688

// ws layout (float units)
#define WS_SIM   0
#define WS_CONF  16384
#define WS_ACC   32768            // 8*2688 = 21504 floats
#define WS_WT    54272            // bf16[2][128][256] = 65536 bf16 = 32768 float slots

typedef __attribute__((ext_vector_type(8))) short bf16x8;
typedef __attribute__((ext_vector_type(4))) float f32x4;

// ---------------------------------------------------------------------------
// Kernel 0: prep — transpose+round w1 (fp32 [k=256][n=128]) to bf16 Wt[mlp][n][k],
// and zero the ws accumulator region. 65536 threads.
// ---------------------------------------------------------------------------
__global__ void prep_kernel(const float* __restrict__ sw1, const float* __restrict__ cw1,
                            short* __restrict__ wt, float* __restrict__ ws_acc)
{
    const int t = blockIdx.x * 256 + threadIdx.x;      // 0..65535
    const int k = t & 255, n = (t >> 8) & 127, mlp = t >> 15;
    const float* w1 = mlp ? cw1 : sw1;
    union { float f; unsigned u; } c; c.f = w1[k * HK_ + n];
    unsigned r = (c.u + 0x7FFF + ((c.u >> 16) & 1)) >> 16;   // RNE to bf16
    wt[t] = (short)r;                                  // coalesced write [mlp][n][k]
    if (t < B_ * ACC_STRIDE) ws_acc[t] = 0.f;
}

// ---------------------------------------------------------------------------
// Kernel 1: dual MLP via bf16 MFMA (16x16x32), 2-term A-split (Ahi+Alo) x Whi.
// Block = 256 threads = 4 waves; block covers 32 rows; wave w: mlp=w>>1, mt=w&1.
// W staged in LDS per K-chunk of 64 (padded rows, 2-way-free bank pattern).
// Fused fp32 layer-2 epilogue: relu(h+b1)·w2 + shfl reduce -> sim / sigmoid conf.
// ---------------------------------------------------------------------------
__launch_bounds__(256)
__global__ void mlp_mfma_kernel(const float* __restrict__ fx, const short* __restrict__ wt,
                                const float* __restrict__ sb1, const float* __restrict__ sw2,
                                const float* __restrict__ sb2, const float* __restrict__ cb1,
                                const float* __restrict__ cw2, const float* __restrict__ cb2,
                                float* __restrict__ sim, float* __restrict__ conf)
{
    __shared__ short lds[2 * 128 * 72];    // 2 mlp x 128 n-rows x (64k + 8 pad) bf16 = 36 KB
    const int tid  = threadIdx.x;
    const int w    = tid >> 6, l = tid & 63;
    const int col  = l & 15, quad = l >> 4;
    const int mlp  = w >> 1, mt = w & 1;
    const int row  = blockIdx.x * 32 + mt * 16 + col;  // A-operand m = lane&15

    f32x4 acc[8];
    #pragma unroll
    for (int nt = 0; nt < 8; ++nt) acc[nt] = (f32x4){0.f, 0.f, 0.f, 0.f};

    const float* fxrow = fx + (size_t)row * H_;

    for (int ch = 0; ch < 4; ++ch) {
        __syncthreads();
        // stage W chunk: 2048 units of 8 bf16 (16 B); coalesced global, aligned LDS
        #pragma unroll
        for (int i = 0; i < 8; ++i) {
            int u  = tid + 256 * i;
            int um = u >> 10, un = (u >> 3) & 127, us = u & 7;
            const short* src = wt + um * 32768 + un * 256 + ch * 64 + us * 8;
            *(uint4*)&lds[um * 9216 + un * 72 + us * 8] = *(const uint4*)src;
        }
        __syncthreads();
        #pragma unroll
        for (int ks = 0; ks < 2; ++ks) {
            const int kg = ch * 64 + ks * 32 + quad * 8;
            float4 a0 = *(const float4*)(fxrow + kg);
            float4 a1 = *(const float4*)(fxrow + kg + 4);
            float af[8] = {a0.x, a0.y, a0.z, a0.w, a1.x, a1.y, a1.z, a1.w};
            bf16x8 ahi, alo;
            #pragma unroll
            for (int i = 0; i < 8; ++i) {
                union { float f; unsigned u; } c; c.f = af[i];
                unsigned hi = c.u >> 16;                       // truncate: lo captures residual
                ahi[i] = (short)hi;
                union { float f; unsigned u; } h2; h2.u = hi << 16;
                union { float f; unsigned u; } c2; c2.f = af[i] - h2.f;
                alo[i] = (short)(c2.u >> 16);
            }
            const short* bbase = lds + mlp * 9216 + ks * 32 + quad * 8;
            #pragma unroll
            for (int nt = 0; nt < 8; ++nt) {
                bf16x8 bf = *(const bf16x8*)(bbase + (nt * 16 + col) * 72);
                acc[nt] = __builtin_amdgcn_mfma_f32_16x16x32_bf16(ahi, bf, acc[nt], 0, 0, 0);
                acc[nt] = __builtin_amdgcn_mfma_f32_16x16x32_bf16(alo, bf, acc[nt], 0, 0, 0);
            }
        }
    }

    // fp32 layer-2 epilogue
    const float* b1 = mlp ? cb1 : sb1;
    const float* w2 = mlp ? cw2 : sw2;
    const float  b2v = mlp ? cb2[0] : sb2[0];
    float p[4] = {0.f, 0.f, 0.f, 0.f};
    #pragma unroll
    for (int nt = 0; nt < 8; ++nt) {
        float b1c = b1[nt * 16 + col];
        float w2c = w2[nt * 16 + col];
        #pragma unroll
        for (int j = 0; j < 4; ++j)
            p[j] += fmaxf(acc[nt][j] + b1c, 0.f) * w2c;
    }
    #pragma unroll
    for (int off = 8; off >= 1; off >>= 1)
        #pragma unroll
        for (int j = 0; j < 4; ++j) p[j] += __shfl_down(p[j], off, 16);

    if (col == 0) {
        #pragma unroll
        for (int j = 0; j < 4; ++j) {
            int r = blockIdx.x * 32 + mt * 16 + quad * 4 + j;   // D row = quad*4+reg
            float v = p[j] + b2v;
            if (mlp == 0) sim[r] = v;
            else          conf[r] = 1.0f / (1.0f + expf(-v));
        }
    }
}

// ---------------------------------------------------------------------------
// Kernel 2: bucketed sums over param_x + softmax-denominator stats.
// Per block: batch b, 64-row chunk. LDS accumulators, atomicAdd flush.
// ---------------------------------------------------------------------------
__launch_bounds__(256)
__global__ void accum_kernel(const float* __restrict__ sim, const int* __restrict__ questions,
                             const float* __restrict__ px, float* __restrict__ ws_acc)
{
    const int b = blockIdx.x;
    const int chunk = blockIdx.y;         // 32 chunks of 64 rows
    const int tid = threadIdx.x;
    const int lane = tid & 63;            // p index
    const int g = tid >> 6;               // group 0..3
    __shared__ float accs[4][ACC_STRIDE];
    for (int s = tid; s < 4 * ACC_STRIDE; s += 256) ((float*)accs)[s] = 0.f;
    __syncthreads();

    const float* simb = sim + b * S_;
    const int*   qb   = questions + b * S_;
    const float* pxb  = px + (size_t)b * S_ * P_;

    float Treg = 0.f;
    const int i0 = chunk * 64 + g;
    for (int t = 0; t < 16; ++t) {
        int i = i0 + 4 * t;
        int qi = qb[i];                       // uniform across group -> broadcast
        float e = expf(simb[i]);
        float v = pxb[(size_t)i * P_ + lane]; // coalesced 256B per group
        Treg += v;
        accs[g][qi * 64 + lane]        += v;       // G_q
        accs[g][(20 + qi) * 64 + lane] += e * v;   // E_q
        if (lane == 0) {
            accs[g][2624 + qi] += e;               // W_q (denominator exp-sum)
            accs[g][2644 + qi] += 1.0f;            // n_q (group size)
        }
    }
    accs[g][2560 + lane] += Treg;                  // T
    __syncthreads();

    float* dst = ws_acc + (size_t)b * ACC_STRIDE;
    for (int s = tid; s < ACC_STRIDE; s += 256) {
        float sum = accs[0][s] + accs[1][s] + accs[2][s] + accs[3][s];
        atomicAdd(dst + s, sum);
    }
}

// ---------------------------------------------------------------------------
// Kernel 3: out = c*px + (1-c) * ((T - G_q + E_q) / denom_q), float4 per thread.
// denom_q = (S - n_q) + W_q computed inline from ws_acc.
// ---------------------------------------------------------------------------
__global__ void output_kernel(const float* __restrict__ px, const float* __restrict__ conf,
                              const int* __restrict__ questions, const float* __restrict__ ws_acc,
                              float* __restrict__ out)
{
    const int idx = blockIdx.x * 256 + threadIdx.x;  // float4 units, 262144 total
    const int row = idx >> 4;                        // b*S + s
    const int p4  = idx & 15;
    const int b   = row >> 11;                       // S = 2048
    const float c = conf[row];
    const int   q = questions[row];
    const float* accb = ws_acc + (size_t)b * ACC_STRIDE;
    const float4 T = *(const float4*)(accb + 2560 + p4 * 4);
    const float4 G = *(const float4*)(accb + q * 64 + p4 * 4);
    const float4 E = *(const float4*)(accb + (20 + q) * 64 + p4 * 4);
    const float denom = ((float)S_ - accb[2644 + q]) + accb[2624 + q];
    const float inv = 1.0f / denom;
    const float4 pv = ((const float4*)px)[idx];
    const float om = 1.0f - c;
    float4 o;
    o.x = c * pv.x + om * ((T.x - G.x + E.x) * inv);
    o.y = c * pv.y + om * ((T.y - G.y + E.y) * inv);
    o.z = c * pv.z + om * ((T.z - G.z + E.z) * inv);
    o.w = c * pv.w + om * ((T.w - G.w + E.w) * inv);
    ((float4*)out)[idx] = o;
}

// ---------------------------------------------------------------------------
extern "C" void kernel_launch(void* const* d_in, const int* in_sizes, int n_in,
                              void* d_out, int out_size, void* d_ws, size_t ws_size,
                              hipStream_t stream) {
    const float* fx  = (const float*)d_in[0];
    const float* px  = (const float*)d_in[1];
    const float* sw1 = (const float*)d_in[2];
    const float* sb1 = (const float*)d_in[3];
    const float* sw2 = (const float*)d_in[4];
    const float* sb2 = (const float*)d_in[5];
    const float* cw1 = (const float*)d_in[6];
    const float* cb1 = (const float*)d_in[7];
    const float* cw2 = (const float*)d_in[8];
    const float* cb2 = (const float*)d_in[9];
    const int* questions = (const int*)d_in[10];
    float* out = (float*)d_out;

    float* ws     = (float*)d_ws;
    float* sim    = ws + WS_SIM;
    float* conf   = ws + WS_CONF;
    float* ws_acc = ws + WS_ACC;
    short* wt     = (short*)(ws + WS_WT);

    prep_kernel<<<256, 256, 0, stream>>>(sw1, cw1, wt, ws_acc);
    mlp_mfma_kernel<<<M_ / 32, 256, 0, stream>>>(fx, wt, sb1, sw2, sb2,
                                                 cb1, cw2, cb2, sim, conf);
    accum_kernel<<<dim3(B_, 32), 256, 0, stream>>>(sim, questions, px, ws_acc);
    output_kernel<<<(M_ * P_ / 4) / 256, 256, 0, stream>>>(px, conf, questions,
                                                           ws_acc, out);
}

// Round 3
// 109.421 us; speedup vs baseline: 1.1729x; 1.0752x over previous
//
#include <hip/hip_runtime.h>
#include <math.h>

#define B_  8
#define S_  2048
#define H_  256
#define HK_ 128
#define P_  64
#define NQ_ 20
#define M_  (B_*S_)          // 16384 rows
// per-batch accumulator: G[20][64]@0, E[20][64]@1280, T[64]@2560, W[20]@2624, n[20]@2644, pad->2688
#define ACC_STRIDE 2688

// ws layout (float units)
#define WS_SIM   0
#define WS_CONF  16384
#define WS_ACC   32768            // 8*2688 = 21504 floats
#define WS_WT    54272            // bf16 frags: 2*8*8*64*8 = 65536 shorts = 32768 float slots

typedef __attribute__((ext_vector_type(8))) short bf16x8;
typedef __attribute__((ext_vector_type(4))) float f32x4;

// ---------------------------------------------------------------------------
// Kernel 0: prep — round w1 (fp32 [k=256][n=128]) RNE to bf16 and scatter into
// MFMA B-fragment order wtf[mlp][kt(8)][nt(8)][lane(64)][j(8)]:
//   lane l -> col=l&15, quad=l>>4;  element j: B[k = kt*32+quad*8+j][n = nt*16+col]
// Also zeros the ws accumulator region. 8192 threads, each writes one 16B frag.
// ---------------------------------------------------------------------------
__global__ void prep_kernel(const float* __restrict__ sw1, const float* __restrict__ cw1,
                            short* __restrict__ wtf, float* __restrict__ ws_acc)
{
    const int t = blockIdx.x * 256 + threadIdx.x;      // 0..8191
    const int l = t & 63, nt = (t >> 6) & 7, kt = (t >> 9) & 7, mlp = t >> 12;
    const int col = l & 15, quad = l >> 4;
    const int n = nt * 16 + col;
    const float* w1 = mlp ? cw1 : sw1;
    short frag[8];
    #pragma unroll
    for (int j = 0; j < 8; ++j) {
        int k = kt * 32 + quad * 8 + j;
        union { float f; unsigned u; } c; c.f = w1[k * HK_ + n];
        frag[j] = (short)((c.u + 0x7FFF + ((c.u >> 16) & 1)) >> 16);   // RNE
    }
    *(uint4*)(wtf + (size_t)t * 8) = *(const uint4*)frag;
    for (int s = t; s < B_ * ACC_STRIDE; s += 8192) ws_acc[s] = 0.f;
}

// ---------------------------------------------------------------------------
// Kernel 1: dual MLP via bf16 MFMA (16x16x32), 2-term A-split (Ahi+Alo).
// NO LDS, no barriers: B-fragments loaded straight from global (L2-broadcast,
// fragment-ordered so each load is a fully coalesced 1KB wave read).
// Block = 4 waves; wave w: mlp=w>>1, row-tile mt=w&1 (32 rows/block).
// Fused fp32 layer-2 epilogue: relu(h+b1)·w2 + shfl reduce -> sim / sigmoid conf.
// ---------------------------------------------------------------------------
__launch_bounds__(256)
__global__ void mlp_mfma_kernel(const float* __restrict__ fx, const short* __restrict__ wtf,
                                const float* __restrict__ sb1, const float* __restrict__ sw2,
                                const float* __restrict__ sb2, const float* __restrict__ cb1,
                                const float* __restrict__ cw2, const float* __restrict__ cb2,
                                float* __restrict__ sim, float* __restrict__ conf)
{
    const int tid  = threadIdx.x;
    const int w    = tid >> 6, l = tid & 63;
    const int col  = l & 15, quad = l >> 4;
    const int mlp  = w >> 1, mt = w & 1;
    const int row  = blockIdx.x * 32 + mt * 16 + col;  // A-operand m = lane&15

    f32x4 acc[8];
    #pragma unroll
    for (int nt = 0; nt < 8; ++nt) acc[nt] = (f32x4){0.f, 0.f, 0.f, 0.f};

    const float* fxrow = fx + (size_t)row * H_;
    const short* wf = wtf + (size_t)mlp * 32768 + (size_t)l * 8;

    #pragma unroll
    for (int kt = 0; kt < 8; ++kt) {
        float4 a0 = *(const float4*)(fxrow + kt * 32 + quad * 8);
        float4 a1 = *(const float4*)(fxrow + kt * 32 + quad * 8 + 4);
        float af[8] = {a0.x, a0.y, a0.z, a0.w, a1.x, a1.y, a1.z, a1.w};
        bf16x8 ahi, alo;
        #pragma unroll
        for (int i = 0; i < 8; ++i) {
            union { float f; unsigned u; } c; c.f = af[i];
            unsigned hi = c.u >> 16;                       // truncate: lo holds residual
            ahi[i] = (short)hi;
            union { float f; unsigned u; } h2; h2.u = hi << 16;
            union { float f; unsigned u; } c2; c2.f = af[i] - h2.f;
            alo[i] = (short)(c2.u >> 16);
        }
        const short* base = wf + (size_t)kt * 4096;
        #pragma unroll
        for (int nt = 0; nt < 8; ++nt) {
            bf16x8 bf = *(const bf16x8*)(base + nt * 512);
            acc[nt] = __builtin_amdgcn_mfma_f32_16x16x32_bf16(ahi, bf, acc[nt], 0, 0, 0);
            acc[nt] = __builtin_amdgcn_mfma_f32_16x16x32_bf16(alo, bf, acc[nt], 0, 0, 0);
        }
    }

    // fp32 layer-2 epilogue
    const float* b1 = mlp ? cb1 : sb1;
    const float* w2 = mlp ? cw2 : sw2;
    const float  b2v = mlp ? cb2[0] : sb2[0];
    float p[4] = {0.f, 0.f, 0.f, 0.f};
    #pragma unroll
    for (int nt = 0; nt < 8; ++nt) {
        float b1c = b1[nt * 16 + col];
        float w2c = w2[nt * 16 + col];
        #pragma unroll
        for (int j = 0; j < 4; ++j)
            p[j] += fmaxf(acc[nt][j] + b1c, 0.f) * w2c;
    }
    #pragma unroll
    for (int off = 8; off >= 1; off >>= 1)
        #pragma unroll
        for (int j = 0; j < 4; ++j) p[j] += __shfl_down(p[j], off, 16);

    if (col == 0) {
        #pragma unroll
        for (int j = 0; j < 4; ++j) {
            int r = blockIdx.x * 32 + mt * 16 + quad * 4 + j;   // D row = quad*4+reg
            float v = p[j] + b2v;
            if (mlp == 0) sim[r] = v;
            else          conf[r] = 1.0f / (1.0f + expf(-v));
        }
    }
}

// ---------------------------------------------------------------------------
// Kernel 2: bucketed sums over param_x + softmax-denominator stats.
// Per block: batch b, 64-row chunk. LDS accumulators, atomicAdd flush.
// ---------------------------------------------------------------------------
__launch_bounds__(256)
__global__ void accum_kernel(const float* __restrict__ sim, const int* __restrict__ questions,
                             const float* __restrict__ px, float* __restrict__ ws_acc)
{
    const int b = blockIdx.x;
    const int chunk = blockIdx.y;         // 32 chunks of 64 rows
    const int tid = threadIdx.x;
    const int lane = tid & 63;            // p index
    const int g = tid >> 6;               // group 0..3
    __shared__ float accs[4][ACC_STRIDE];
    for (int s = tid; s < 4 * ACC_STRIDE; s += 256) ((float*)accs)[s] = 0.f;
    __syncthreads();

    const float* simb = sim + b * S_;
    const int*   qb   = questions + b * S_;
    const float* pxb  = px + (size_t)b * S_ * P_;

    float Treg = 0.f;
    const int i0 = chunk * 64 + g;
    for (int t = 0; t < 16; ++t) {
        int i = i0 + 4 * t;
        int qi = qb[i];                       // uniform across group -> broadcast
        float e = expf(simb[i]);
        float v = pxb[(size_t)i * P_ + lane]; // coalesced 256B per group
        Treg += v;
        accs[g][qi * 64 + lane]        += v;       // G_q
        accs[g][(20 + qi) * 64 + lane] += e * v;   // E_q
        if (lane == 0) {
            accs[g][2624 + qi] += e;               // W_q (denominator exp-sum)
            accs[g][2644 + qi] += 1.0f;            // n_q (group size)
        }
    }
    accs[g][2560 + lane] += Treg;                  // T
    __syncthreads();

    float* dst = ws_acc + (size_t)b * ACC_STRIDE;
    for (int s = tid; s < ACC_STRIDE; s += 256) {
        float sum = accs[0][s] + accs[1][s] + accs[2][s] + accs[3][s];
        atomicAdd(dst + s, sum);
    }
}

// ---------------------------------------------------------------------------
// Kernel 3: out = c*px + (1-c) * ((T - G_q + E_q) / denom_q), float4 per thread.
// denom_q = (S - n_q) + W_q computed inline from ws_acc.
// ---------------------------------------------------------------------------
__global__ void output_kernel(const float* __restrict__ px, const float* __restrict__ conf,
                              const int* __restrict__ questions, const float* __restrict__ ws_acc,
                              float* __restrict__ out)
{
    const int idx = blockIdx.x * 256 + threadIdx.x;  // float4 units, 262144 total
    const int row = idx >> 4;                        // b*S + s
    const int p4  = idx & 15;
    const int b   = row >> 11;                       // S = 2048
    const float c = conf[row];
    const int   q = questions[row];
    const float* accb = ws_acc + (size_t)b * ACC_STRIDE;
    const float4 T = *(const float4*)(accb + 2560 + p4 * 4);
    const float4 G = *(const float4*)(accb + q * 64 + p4 * 4);
    const float4 E = *(const float4*)(accb + (20 + q) * 64 + p4 * 4);
    const float denom = ((float)S_ - accb[2644 + q]) + accb[2624 + q];
    const float inv = 1.0f / denom;
    const float4 pv = ((const float4*)px)[idx];
    const float om = 1.0f - c;
    float4 o;
    o.x = c * pv.x + om * ((T.x - G.x + E.x) * inv);
    o.y = c * pv.y + om * ((T.y - G.y + E.y) * inv);
    o.z = c * pv.z + om * ((T.z - G.z + E.z) * inv);
    o.w = c * pv.w + om * ((T.w - G.w + E.w) * inv);
    ((float4*)out)[idx] = o;
}

// ---------------------------------------------------------------------------
extern "C" void kernel_launch(void* const* d_in, const int* in_sizes, int n_in,
                              void* d_out, int out_size, void* d_ws, size_t ws_size,
                              hipStream_t stream) {
    const float* fx  = (const float*)d_in[0];
    const float* px  = (const float*)d_in[1];
    const float* sw1 = (const float*)d_in[2];
    const float* sb1 = (const float*)d_in[3];
    const float* sw2 = (const float*)d_in[4];
    const float* sb2 = (const float*)d_in[5];
    const float* cw1 = (const float*)d_in[6];
    const float* cb1 = (const float*)d_in[7];
    const float* cw2 = (const float*)d_in[8];
    const float* cb2 = (const float*)d_in[9];
    const int* questions = (const int*)d_in[10];
    float* out = (float*)d_out;

    float* ws     = (float*)d_ws;
    float* sim    = ws + WS_SIM;
    float* conf   = ws + WS_CONF;
    float* ws_acc = ws + WS_ACC;
    short* wtf    = (short*)(ws + WS_WT);

    prep_kernel<<<32, 256, 0, stream>>>(sw1, cw1, wtf, ws_acc);
    mlp_mfma_kernel<<<M_ / 32, 256, 0, stream>>>(fx, wtf, sb1, sw2, sb2,
                                                 cb1, cw2, cb2, sim, conf);
    accum_kernel<<<dim3(B_, 32), 256, 0, stream>>>(sim, questions, px, ws_acc);
    output_kernel<<<(M_ * P_ / 4) / 256, 256, 0, stream>>>(px, conf, questions,
                                                           ws_acc, out);
}